// Round 1
// baseline (446.141 us; speedup 1.0000x reference)
//
#include <hip/hip_runtime.h>

// Problem constants: B=8,T=48 -> M=384 rows; N=512 nodes; IN=OUT=256; GR=16; NR=8.
// out[m][n][o] = sum_i x[m][n][i]*Weff_n[o][i] + b[o]
// Weff_n = W + gA·gB/16 + nA[n]·nB[n]/8  (folded per workgroup into LDS as bf16)

typedef __attribute__((ext_vector_type(4))) float f32x4;
typedef __attribute__((ext_vector_type(8))) short short8;

__device__ __forceinline__ unsigned short f2bf(float f) {
    unsigned int u = __builtin_bit_cast(unsigned int, f);
    u += 0x7fffu + ((u >> 16) & 1u);          // round-to-nearest-even
    return (unsigned short)(u >> 16);
}

__global__ __launch_bounds__(512, 2) void fused_node_lora(
    const float* __restrict__ x, const float* __restrict__ W,
    const float* __restrict__ bias, const float* __restrict__ gA,
    const float* __restrict__ gB, const float* __restrict__ nA,
    const float* __restrict__ nB, float* __restrict__ out)
{
    extern __shared__ __align__(16) char smem[];   // Weff bf16 [256 o][256 i], XOR-swizzled, 128 KB
    const int n    = blockIdx.x;                   // node
    const int tid  = threadIdx.x;
    const int lane = tid & 63;
    const int w    = tid >> 6;                     // wave 0..7
    const int l15  = lane & 15;
    const int kblk = lane >> 4;                    // 0..3

    // ---------------- fold phase: Weff into LDS via one K=32 MFMA step ----------------
    {
        // A' (IN x 32): k<16 -> gA[i][k]/16 ; 16<=k<24 -> nA[n][i][k-16]/8 ; k>=24 -> 0
        short8 afr[2];
        #pragma unroll
        for (int t = 0; t < 2; ++t) {
            const int i = (w * 2 + t) * 16 + l15;
            const float* ap = (kblk == 2) ? (nA + ((long)n * 256 + i) * 8)
                                          : (gA + (long)i * 16 + (kblk & 1) * 8);
            const float sc = (kblk == 2) ? 0.125f : ((kblk == 3) ? 0.0f : 0.0625f);
            const float4 q0 = *(const float4*)(ap);
            const float4 q1 = *(const float4*)(ap + 4);
            short8 a;
            a[0] = (short)f2bf(q0.x * sc); a[1] = (short)f2bf(q0.y * sc);
            a[2] = (short)f2bf(q0.z * sc); a[3] = (short)f2bf(q0.w * sc);
            a[4] = (short)f2bf(q1.x * sc); a[5] = (short)f2bf(q1.y * sc);
            a[6] = (short)f2bf(q1.z * sc); a[7] = (short)f2bf(q1.w * sc);
            afr[t] = a;
        }
        // B' (32 x OUT): k<16 -> gB[k][o] ; 16<=k<24 -> nB[n][k-16][o] ; k>=24 -> (don't care, A'=0)
        for (int ot = 0; ot < 16; ++ot) {
            const int o = ot * 16 + l15;
            const float* bp = (kblk == 0) ? (gB + o)
                             : (kblk == 1) ? (gB + 2048 + o)
                                           : (nB + (long)n * 2048 + o);
            short8 bfr;
            #pragma unroll
            for (int j = 0; j < 8; ++j) bfr[j] = (short)f2bf(bp[j * 256]);
            const f32x4 zero = {0.f, 0.f, 0.f, 0.f};
            f32x4 c0 = __builtin_amdgcn_mfma_f32_16x16x32_bf16(afr[0], bfr, zero, 0, 0, 0);
            f32x4 c1 = __builtin_amdgcn_mfma_f32_16x16x32_bf16(afr[1], bfr, zero, 0, 0, 0);
            #pragma unroll
            for (int t = 0; t < 2; ++t) {
                const f32x4 c = t ? c1 : c0;
                const int ib = (w * 2 + t) * 16 + kblk * 4;   // 4 consecutive i per lane
                const float4 wv = *(const float4*)(W + (long)o * 256 + ib);
                unsigned int lo = (unsigned int)f2bf(wv.x + c[0]) |
                                  ((unsigned int)f2bf(wv.y + c[1]) << 16);
                unsigned int hi = (unsigned int)f2bf(wv.z + c[2]) |
                                  ((unsigned int)f2bf(wv.w + c[3]) << 16);
                int byte = (o << 9) + (ib << 1);
                byte ^= ((o & 7) << 4);                        // swizzle (conflict-free r/w)
                *reinterpret_cast<uint2*>(smem + byte) = make_uint2(lo, hi);
            }
        }
    }
    __syncthreads();

    // ---------------- main GEMM: x (global, 2-deep prefetch) x Weff (LDS) ----------------
    float bcol[16];
    #pragma unroll
    for (int ot = 0; ot < 16; ++ot) bcol[ot] = bias[ot * 16 + l15];

    for (int rt = w; rt < 24; rt += 8) {           // 24 row-tiles of 16, 3 per wave
        const int m = rt * 16 + l15;
        const float* xrow = x + ((long)m * 512 + n) * 256 + kblk * 8;
        float4 b0a = *(const float4*)(xrow);
        float4 b0b = *(const float4*)(xrow + 4);
        float4 b1a = *(const float4*)(xrow + 32);
        float4 b1b = *(const float4*)(xrow + 36);
        f32x4 acc[16];
        #pragma unroll
        for (int ot = 0; ot < 16; ++ot) { const f32x4 z = {0.f,0.f,0.f,0.f}; acc[ot] = z; }

        #pragma unroll
        for (int kt = 0; kt < 8; ++kt) {
            const float4 ca = (kt & 1) ? b1a : b0a;
            const float4 cb = (kt & 1) ? b1b : b0b;
            short8 af;
            af[0] = (short)f2bf(ca.x); af[1] = (short)f2bf(ca.y);
            af[2] = (short)f2bf(ca.z); af[3] = (short)f2bf(ca.w);
            af[4] = (short)f2bf(cb.x); af[5] = (short)f2bf(cb.y);
            af[6] = (short)f2bf(cb.z); af[7] = (short)f2bf(cb.w);
            if (kt < 6) {                          // prefetch kt+2
                const float4* p = (const float4*)(xrow + (kt + 2) * 32);
                if (kt & 1) { b1a = p[0]; b1b = p[1]; }
                else        { b0a = p[0]; b0b = p[1]; }
            }
            const unsigned int kaddr =
                ((((unsigned)l15 << 9) | ((unsigned)kt << 6) | ((unsigned)kblk << 4))
                 ^ (((unsigned)(l15 & 7)) << 4));
            #pragma unroll
            for (int ot = 0; ot < 16; ++ot) {
                const short8 bf = *reinterpret_cast<const short8*>(smem + kaddr + ot * 8192);
                acc[ot] = __builtin_amdgcn_mfma_f32_16x16x32_bf16(af, bf, acc[ot], 0, 0, 0);
            }
        }
        // epilogue: D rows = m (rt*16 + kblk*4 + r), cols = o (ot*16 + l15)
        const int mb = rt * 16 + kblk * 4;
        float* obase = out + ((long)mb * 512 + n) * 256 + l15;
        #pragma unroll
        for (int ot = 0; ot < 16; ++ot) {
            #pragma unroll
            for (int r = 0; r < 4; ++r) {
                obase[(long)r * 131072 + ot * 16] = acc[ot][r] + bcol[ot];
            }
        }
    }
}

extern "C" void kernel_launch(void* const* d_in, const int* in_sizes, int n_in,
                              void* d_out, int out_size, void* d_ws, size_t ws_size,
                              hipStream_t stream) {
    const float* x  = (const float*)d_in[0];
    const float* W  = (const float*)d_in[1];
    const float* b  = (const float*)d_in[2];
    const float* gA = (const float*)d_in[3];
    const float* gB = (const float*)d_in[4];
    const float* nA = (const float*)d_in[5];
    const float* nB = (const float*)d_in[6];
    float* out = (float*)d_out;
    (void)hipFuncSetAttribute((const void*)fused_node_lora,
                              hipFuncAttributeMaxDynamicSharedMemorySize, 131072);
    fused_node_lora<<<dim3(512), dim3(512), 131072, stream>>>(x, W, b, gA, gB, nA, nB, out);
}

// Round 2
// 125.530 us; speedup vs baseline: 3.5541x; 3.5541x over previous
//
#include <hip/hip_runtime.h>

// out[m][n][o] = sum_i x[m][n][i]*Weff_n[o][i] + b[o]
// Weff_n = W + gA·gB/16 + nA[n]·nB[n]/8  (folded per workgroup into LDS as bf16)
// M=B*T=384 rows, N=512 nodes, IN=OUT=256.

typedef __attribute__((ext_vector_type(4))) float f32x4;
typedef __attribute__((ext_vector_type(8))) short short8;

__device__ __forceinline__ unsigned short f2bf(float f) {
    unsigned int u = __builtin_bit_cast(unsigned int, f);
    u += 0x7fffu + ((u >> 16) & 1u);          // round-to-nearest-even
    return (unsigned short)(u >> 16);
}

__device__ __forceinline__ short8 cvt8(f32x4 a, f32x4 b) {
    short8 r;
    r[0] = (short)f2bf(a[0]); r[1] = (short)f2bf(a[1]);
    r[2] = (short)f2bf(a[2]); r[3] = (short)f2bf(a[3]);
    r[4] = (short)f2bf(b[0]); r[5] = (short)f2bf(b[1]);
    r[6] = (short)f2bf(b[2]); r[7] = (short)f2bf(b[3]);
    return r;
}

__global__ __launch_bounds__(512, 1) void fused_node_lora(
    const float* __restrict__ x, const float* __restrict__ W,
    const float* __restrict__ bias, const float* __restrict__ gA,
    const float* __restrict__ gB, const float* __restrict__ nA,
    const float* __restrict__ nB, float* __restrict__ out)
{
    extern __shared__ __align__(16) char smem[];   // Weff bf16 [256 o][256 i], XOR-swizzled, 128 KB
    const int n    = blockIdx.x;                   // node
    const int tid  = threadIdx.x;
    const int lane = tid & 63;
    const int w    = tid >> 6;                     // wave 0..7
    const int l15  = lane & 15;
    const int kblk = lane >> 4;                    // 0..3

    // ---------------- fold phase: Weff into LDS via one K=32 MFMA step ----------------
    {
        // A' (IN x 32): k<16 -> gA[i][k]/16 ; 16<=k<24 -> nA[n][i][k-16]/8 ; k>=24 -> 0
        short8 afr[2];
        #pragma unroll
        for (int t = 0; t < 2; ++t) {
            const int i = (w * 2 + t) * 16 + l15;
            const float* ap = (kblk == 2) ? (nA + ((long)n * 256 + i) * 8)
                                          : (gA + (long)i * 16 + (kblk & 1) * 8);
            const float sc = (kblk == 2) ? 0.125f : ((kblk == 3) ? 0.0f : 0.0625f);
            const float4 q0 = *(const float4*)(ap);
            const float4 q1 = *(const float4*)(ap + 4);
            short8 a;
            a[0] = (short)f2bf(q0.x * sc); a[1] = (short)f2bf(q0.y * sc);
            a[2] = (short)f2bf(q0.z * sc); a[3] = (short)f2bf(q0.w * sc);
            a[4] = (short)f2bf(q1.x * sc); a[5] = (short)f2bf(q1.y * sc);
            a[6] = (short)f2bf(q1.z * sc); a[7] = (short)f2bf(q1.w * sc);
            afr[t] = a;
        }
        // B' (32 x OUT): k<16 -> gB[k][o] ; 16<=k<24 -> nB[n][k-16][o] ; k>=24 -> (don't care, A'=0)
        for (int ot = 0; ot < 16; ++ot) {
            const int o = ot * 16 + l15;
            const float* bp = (kblk == 0) ? (gB + o)
                             : (kblk == 1) ? (gB + 2048 + o)
                                           : (nB + (long)n * 2048 + o);
            short8 bfr;
            #pragma unroll
            for (int j = 0; j < 8; ++j) bfr[j] = (short)f2bf(bp[j * 256]);
            const f32x4 zero = {0.f, 0.f, 0.f, 0.f};
            f32x4 c0 = __builtin_amdgcn_mfma_f32_16x16x32_bf16(afr[0], bfr, zero, 0, 0, 0);
            f32x4 c1 = __builtin_amdgcn_mfma_f32_16x16x32_bf16(afr[1], bfr, zero, 0, 0, 0);
            #pragma unroll
            for (int t = 0; t < 2; ++t) {
                const f32x4 c = t ? c1 : c0;
                const int ib = (w * 2 + t) * 16 + kblk * 4;   // 4 consecutive i per lane
                const float4 wv = *(const float4*)(W + (long)o * 256 + ib);
                unsigned int lo = (unsigned int)f2bf(wv.x + c[0]) |
                                  ((unsigned int)f2bf(wv.y + c[1]) << 16);
                unsigned int hi = (unsigned int)f2bf(wv.z + c[2]) |
                                  ((unsigned int)f2bf(wv.w + c[3]) << 16);
                int byte = (o << 9) + (ib << 1);
                byte ^= ((o & 7) << 4);                        // swizzle (conflict-free r/w)
                *reinterpret_cast<uint2*>(smem + byte) = make_uint2(lo, hi);
            }
        }
    }
    __syncthreads();

    // ---------------- main GEMM: x (global, nt, 3-deep prefetch) x Weff (LDS) ----------------
    // Transposed MFMA: D = mfma(Weff_frag as A, x_frag as B) -> D[o-row][m-col];
    // lane holds col m = rt*16+l15, rows o = ot*16 + kblk*4 + r  => dwordx4 stores.
    const float* xbase = x + ((long)(w * 16 + l15) * 512 + n) * 256 + kblk * 8;
    const long RSTR = 128L * 512 * 256;            // +8 row-tiles (128 m-rows) in floats

    f32x4 pfa[3], pfb[3];
    #define LDX(t) do {                                                        \
        const f32x4* _p = (const f32x4*)(xbase + ((t) >> 3) * RSTR + ((t) & 7) * 32); \
        pfa[(t) % 3] = __builtin_nontemporal_load(_p);                         \
        pfb[(t) % 3] = __builtin_nontemporal_load(_p + 1);                     \
    } while (0)

    LDX(0); LDX(1); LDX(2);

    #pragma unroll
    for (int rtl = 0; rtl < 3; ++rtl) {
        f32x4 acc[16];
        #pragma unroll
        for (int ot = 0; ot < 16; ++ot) { const f32x4 z = {0.f,0.f,0.f,0.f}; acc[ot] = z; }

        #pragma unroll
        for (int kt = 0; kt < 8; ++kt) {
            const int t = rtl * 8 + kt;
            const short8 af = cvt8(pfa[t % 3], pfb[t % 3]);
            if (t + 3 < 24) LDX(t + 3);            // spans row-tile boundary: no cold start
            const unsigned int kaddr =
                ((((unsigned)l15 << 9) | ((unsigned)kt << 6) | ((unsigned)kblk << 4))
                 ^ (((unsigned)(l15 & 7)) << 4));
            #pragma unroll
            for (int ot = 0; ot < 16; ++ot) {
                const short8 bf = *reinterpret_cast<const short8*>(smem + kaddr + ot * 8192);
                acc[ot] = __builtin_amdgcn_mfma_f32_16x16x32_bf16(bf, af, acc[ot], 0, 0, 0);
            }
        }

        // epilogue: lane writes out[m][n][ot*16 + kblk*4 .. +3], m = rt*16 + l15
        const int rt = w + rtl * 8;
        float* obase = out + ((long)(rt * 16 + l15) * 512 + n) * 256 + kblk * 4;
        #pragma unroll
        for (int ot = 0; ot < 16; ++ot) {
            const f32x4 bv = *(const f32x4*)(bias + ot * 16 + kblk * 4);
            f32x4 v = acc[ot];
            v[0] += bv[0]; v[1] += bv[1]; v[2] += bv[2]; v[3] += bv[3];
            __builtin_nontemporal_store(v, (f32x4*)(obase + ot * 16));
        }
    }
    #undef LDX
}

extern "C" void kernel_launch(void* const* d_in, const int* in_sizes, int n_in,
                              void* d_out, int out_size, void* d_ws, size_t ws_size,
                              hipStream_t stream) {
    const float* x  = (const float*)d_in[0];
    const float* W  = (const float*)d_in[1];
    const float* b  = (const float*)d_in[2];
    const float* gA = (const float*)d_in[3];
    const float* gB = (const float*)d_in[4];
    const float* nA = (const float*)d_in[5];
    const float* nB = (const float*)d_in[6];
    float* out = (float*)d_out;
    (void)hipFuncSetAttribute((const void*)fused_node_lora,
                              hipFuncAttributeMaxDynamicSharedMemorySize, 131072);
    fused_node_lora<<<dim3(512), dim3(512), 131072, stream>>>(x, W, b, gA, gB, nA, nB, out);
}

// Round 3
// 107.869 us; speedup vs baseline: 4.1360x; 1.1637x over previous
//
#include <hip/hip_runtime.h>

// out[m][n][o] = sum_i x[m][n][i]*Weff_n[o][i] + b[o]
// Weff_n = W + gA·gB/16 + nA[n]·nB[n]/8  (folded per workgroup into LDS as bf16)
// M=B*T=384 rows, N=512 nodes, IN=OUT=256.
//
// Main loop: waves in 4(m) x 2(o) grid. Each wave register-blocks 3 row-tiles
// (2 passes of 3 = 6 tiles) for its 8-of-16 ot slice: per kt-step 8 LDS
// B-fragment reads feed 24 MFMAs (3x amortization vs round 2).

typedef __attribute__((ext_vector_type(4))) float f32x4;
typedef __attribute__((ext_vector_type(8))) short short8;

__device__ __forceinline__ unsigned short f2bf(float f) {
    unsigned int u = __builtin_bit_cast(unsigned int, f);
    u += 0x7fffu + ((u >> 16) & 1u);          // round-to-nearest-even
    return (unsigned short)(u >> 16);
}

__device__ __forceinline__ short8 cvt8(f32x4 a, f32x4 b) {
    short8 r;
    r[0] = (short)f2bf(a[0]); r[1] = (short)f2bf(a[1]);
    r[2] = (short)f2bf(a[2]); r[3] = (short)f2bf(a[3]);
    r[4] = (short)f2bf(b[0]); r[5] = (short)f2bf(b[1]);
    r[6] = (short)f2bf(b[2]); r[7] = (short)f2bf(b[3]);
    return r;
}

__global__ __launch_bounds__(512, 1) void fused_node_lora(
    const float* __restrict__ x, const float* __restrict__ W,
    const float* __restrict__ bias, const float* __restrict__ gA,
    const float* __restrict__ gB, const float* __restrict__ nA,
    const float* __restrict__ nB, float* __restrict__ out)
{
    extern __shared__ __align__(16) char smem[];   // Weff bf16 [256 o][256 i], XOR-swizzled, 128 KB
    const int n    = blockIdx.x;                   // node
    const int tid  = threadIdx.x;
    const int lane = tid & 63;
    const int w    = tid >> 6;                     // wave 0..7
    const int l15  = lane & 15;
    const int kblk = lane >> 4;                    // 0..3

    // ---------------- fold phase: Weff into LDS via one K=32 MFMA step ----------------
    {
        // A' (IN x 32): k<16 -> gA[i][k]/16 ; 16<=k<24 -> nA[n][i][k-16]/8 ; k>=24 -> 0
        short8 afr[2];
        #pragma unroll
        for (int t = 0; t < 2; ++t) {
            const int i = (w * 2 + t) * 16 + l15;
            const float* ap = (kblk == 2) ? (nA + ((long)n * 256 + i) * 8)
                                          : (gA + (long)i * 16 + (kblk & 1) * 8);
            const float sc = (kblk == 2) ? 0.125f : ((kblk == 3) ? 0.0f : 0.0625f);
            const float4 q0 = *(const float4*)(ap);
            const float4 q1 = *(const float4*)(ap + 4);
            short8 a;
            a[0] = (short)f2bf(q0.x * sc); a[1] = (short)f2bf(q0.y * sc);
            a[2] = (short)f2bf(q0.z * sc); a[3] = (short)f2bf(q0.w * sc);
            a[4] = (short)f2bf(q1.x * sc); a[5] = (short)f2bf(q1.y * sc);
            a[6] = (short)f2bf(q1.z * sc); a[7] = (short)f2bf(q1.w * sc);
            afr[t] = a;
        }
        // B' (32 x OUT): k<16 -> gB[k][o] ; 16<=k<24 -> nB[n][k-16][o] ; k>=24 -> (don't care, A'=0)
        for (int ot = 0; ot < 16; ++ot) {
            const int o = ot * 16 + l15;
            const float* bp = (kblk == 0) ? (gB + o)
                             : (kblk == 1) ? (gB + 2048 + o)
                                           : (nB + (long)n * 2048 + o);
            short8 bfr;
            #pragma unroll
            for (int j = 0; j < 8; ++j) bfr[j] = (short)f2bf(bp[j * 256]);
            const f32x4 zero = {0.f, 0.f, 0.f, 0.f};
            f32x4 c0 = __builtin_amdgcn_mfma_f32_16x16x32_bf16(afr[0], bfr, zero, 0, 0, 0);
            f32x4 c1 = __builtin_amdgcn_mfma_f32_16x16x32_bf16(afr[1], bfr, zero, 0, 0, 0);
            #pragma unroll
            for (int t = 0; t < 2; ++t) {
                const f32x4 c = t ? c1 : c0;
                const int ib = (w * 2 + t) * 16 + kblk * 4;   // 4 consecutive i per lane
                const float4 wv = *(const float4*)(W + (long)o * 256 + ib);
                unsigned int lo = (unsigned int)f2bf(wv.x + c[0]) |
                                  ((unsigned int)f2bf(wv.y + c[1]) << 16);
                unsigned int hi = (unsigned int)f2bf(wv.z + c[2]) |
                                  ((unsigned int)f2bf(wv.w + c[3]) << 16);
                int byte = (o << 9) + (ib << 1);
                byte ^= ((o & 7) << 4);                        // swizzle (conflict-free r/w)
                *reinterpret_cast<uint2*>(smem + byte) = make_uint2(lo, hi);
            }
        }
    }
    __syncthreads();

    // ---------------- main GEMM ----------------
    const int wm = w & 3;                          // m-group: 6 row-tiles (2 passes of 3)
    const int wo = w >> 2;                         // o-half: ot = wo*8 .. wo*8+7
    const long TSTR = 16L * 512 * 256;             // +16 m-rows in floats
    const float* xb = x + ((long)(wm * 96 + l15) * 512 + n) * 256 + kblk * 8;

    f32x4 buf[3][3][2];                            // [depth%3][tile j][half]
    #define LDX(s2) do {                                                          \
        const int _p = (s2) >> 3, _k = (s2) & 7;                                  \
        _Pragma("unroll")                                                         \
        for (int _j = 0; _j < 3; ++_j) {                                          \
            const f32x4* _q = (const f32x4*)(xb + (long)(_p * 3 + _j) * TSTR + _k * 32); \
            buf[(s2) % 3][_j][0] = _q[0];                                         \
            buf[(s2) % 3][_j][1] = _q[1];                                         \
        } } while (0)

    LDX(0); LDX(1); LDX(2);

    #pragma unroll
    for (int p = 0; p < 2; ++p) {
        f32x4 acc[3][8];
        #pragma unroll
        for (int j = 0; j < 3; ++j)
            #pragma unroll
            for (int oi = 0; oi < 8; ++oi) { const f32x4 z = {0.f,0.f,0.f,0.f}; acc[j][oi] = z; }

        #pragma unroll
        for (int kt = 0; kt < 8; ++kt) {
            const int s = p * 8 + kt;
            short8 af[3];
            #pragma unroll
            for (int j = 0; j < 3; ++j) af[j] = cvt8(buf[s % 3][j][0], buf[s % 3][j][1]);
            if (s + 3 < 16) LDX(s + 3);            // spans pass boundary: no cold start
            const unsigned int kaddr =
                ((((unsigned)l15 << 9) | ((unsigned)kt << 6) | ((unsigned)kblk << 4))
                 ^ (((unsigned)(l15 & 7)) << 4));
            #pragma unroll
            for (int oi = 0; oi < 8; ++oi) {
                const short8 bf = *reinterpret_cast<const short8*>(
                    smem + kaddr + (unsigned)(wo * 8 + oi) * 8192u);
                #pragma unroll
                for (int j = 0; j < 3; ++j)
                    acc[j][oi] = __builtin_amdgcn_mfma_f32_16x16x32_bf16(bf, af[j], acc[j][oi], 0, 0, 0);
            }
        }

        // epilogue: lane writes out[m][n][ot*16 + kblk*4 .. +3], m = tile*16 + l15
        #pragma unroll
        for (int oi = 0; oi < 8; ++oi) {
            const int ot = wo * 8 + oi;
            const f32x4 bv = *(const f32x4*)(bias + ot * 16 + kblk * 4);
            #pragma unroll
            for (int j = 0; j < 3; ++j) {
                f32x4 v = acc[j][oi];
                v[0] += bv[0]; v[1] += bv[1]; v[2] += bv[2]; v[3] += bv[3];
                float* ob = out + ((long)((wm * 6 + p * 3 + j) * 16 + l15) * 512 + n) * 256
                            + ot * 16 + kblk * 4;
                __builtin_nontemporal_store(v, (f32x4*)ob);
            }
        }
    }
    #undef LDX
}

extern "C" void kernel_launch(void* const* d_in, const int* in_sizes, int n_in,
                              void* d_out, int out_size, void* d_ws, size_t ws_size,
                              hipStream_t stream) {
    const float* x  = (const float*)d_in[0];
    const float* W  = (const float*)d_in[1];
    const float* b  = (const float*)d_in[2];
    const float* gA = (const float*)d_in[3];
    const float* gB = (const float*)d_in[4];
    const float* nA = (const float*)d_in[5];
    const float* nB = (const float*)d_in[6];
    float* out = (float*)d_out;
    (void)hipFuncSetAttribute((const void*)fused_node_lora,
                              hipFuncAttributeMaxDynamicSharedMemorySize, 131072);
    fused_node_lora<<<dim3(512), dim3(512), 131072, stream>>>(x, W, b, gA, gB, nA, nB, out);
}